// Round 10
// baseline (2028.595 us; speedup 1.0000x reference)
//
#include <hip/hip_runtime.h>
#include <math.h>

#define N_VAR 8192
#define N_CHK 4096
#define DV 3
#define N_EDGE (N_VAR * DV)
#define BATCH 128
#define T_ITERS 30
#define ELLW 24
#define SLOT_MAX (N_EDGE + 3 * N_CHK)   /* 36864: sum of padded degs bound */
#define NWK 128                          /* transpose worker blocks */

#define LOG2E 1.44269504088896340736f
#define LN2   0.69314718055994530942f

typedef _Float16 h4 __attribute__((ext_vector_type(4)));

// tanh(x/2), sign preserved, |t| floored at 1e-7 (matches reference clamp);
// x pre-clipped to [-15,15]
__device__ __forceinline__ float tanh_half(float x) {
    float ex = __builtin_amdgcn_exp2f(x * LOG2E);              // e^x
    float t = 1.0f - 2.0f * __builtin_amdgcn_rcpf(ex + 1.0f);
    float s = (x < 0.0f) ? -1.0f : 1.0f;
    return s * fmaxf(fabsf(t), 1e-7f);
}

// 2*atanh(clip(p)) — reference's clip(-1+eps, 1-eps) then 2 atanh
__device__ __forceinline__ float atanh2(float p) {
    const float lim = 1.0f - 1e-7f;
    p = fminf(fmaxf(p, -lim), lim);
    return (__builtin_amdgcn_logf(1.0f + p) -
            __builtin_amdgcn_logf(1.0f - p)) * LN2;
}

// Newton-refined reciprocal (validated R8/R9, absmax 0.125)
__device__ __forceinline__ float rcp_nr(float x) {
    float r = __builtin_amdgcn_rcpf(x);
    return r * (2.0f - x * r);
}

// ---------------- fused graph build (one block, staged via syncthreads) -----
// Each global array is written in one stage and first READ in a later stage
// (cold L1 -> L2 -> correct). deg/hist/cursor/chk_base live in LDS.

__global__ __launch_bounds__(1024) void k_setup(
        const int* __restrict__ edge_chk,
        int* __restrict__ ell_e,        // N_CHK*ELLW global scratch
        int* __restrict__ slot_e,       // N_EDGE global scratch
        int* __restrict__ s_desc_g,     // N_CHK sorted check descriptors
        int4* __restrict__ slot4) {     // N_VAR
    __shared__ int deg[N_CHK];          // 16 KB
    __shared__ int chk_base_s[N_CHK];   // 16 KB
    __shared__ int hist[32], cursor[32], bbase[32], soff[32];
    const int tid = threadIdx.x;

    for (int i = tid; i < N_CHK; i += 1024) deg[i] = 0;
    if (tid < 32) { hist[tid] = 0; cursor[tid] = 0; }
    __syncthreads();

    // stage 0: ELL scatter (order within a check is arbitrary — math is
    // per-edge-slot consistent, so any order is fine)
    for (int e = tid; e < N_EDGE; e += 1024) {
        int c = edge_chk[e];
        int pos = atomicAdd(&deg[c], 1);
        if (pos < ELLW) ell_e[c * ELLW + pos] = e;
    }
    __syncthreads();

    // stage 1: degree histogram (clamped)
    for (int c = tid; c < N_CHK; c += 1024) {
        int d = deg[c]; if (d > ELLW) { d = ELLW; deg[c] = d; }
        atomicAdd(&hist[d], 1);
    }
    __syncthreads();

    // stage 2: bucket bases (serial, 25 buckets)
    if (tid == 0) {
        int cb = 0, sb = 0;
        for (int d = 0; d <= ELLW; ++d) {
            bbase[d] = cb; soff[d] = sb;
            int pd = (d + 3) & ~3;
            cb += hist[d];
            sb += (d == 0) ? 0 : hist[d] * pd;
        }
    }
    __syncthreads();

    // stage 3: place checks into degree-sorted order, padded slot bases
    for (int c = tid; c < N_CHK; c += 1024) {
        int d = deg[c];
        int pd = (d + 3) & ~3;
        int pos = atomicAdd(&cursor[d], 1);
        int i = bbase[d] + pos;
        int base = soff[d] + pos * pd;
        s_desc_g[i] = (base << 5) | d;
        chk_base_s[c] = base;
    }
    __syncthreads();

    // stage 4: slot of each edge
    for (int gid = tid; gid < N_CHK * ELLW; gid += 1024) {
        int c = gid / ELLW;
        int j = gid - c * ELLW;
        if (j < deg[c]) slot_e[ell_e[gid]] = chk_base_s[c] + j;
    }
    __syncthreads();

    // stage 5: per-variable slot triplets
    for (int v = tid; v < N_VAR; v += 1024) {
        int4 s;
        s.x = slot_e[3 * v + 0];
        s.y = slot_e[3 * v + 1];
        s.z = slot_e[3 * v + 2];
        s.w = 0;
        slot4[v] = s;
    }
}

// ---------------- fused BP + transpose ---------------------------------------
// Blocks 0..127: per-batch-element BP (R9-validated structure, in-place LDS
// msg, degree-sorted checks, v2c in f32 regs). After each posterior slice is
// fully stored (fp16, (t,b,v) layout), tid0 does release: threadfence (L2
// writeback) + agent-scope atomicAdd(flags[t]).
// Blocks 128..255: transpose workers on the idle CUs. Wait flags[t]==128
// (acquire), then transpose slice t to the final (t,v,b) f32 layout.
// BP never waits on workers -> no deadlock under any block placement.

__global__ __launch_bounds__(1024) void k_fused(
        const float* __restrict__ chn,
        const float* __restrict__ gamma_logit,
        const int4* __restrict__ slot4,
        const int* __restrict__ s_desc_g,
        _Float16* __restrict__ outT,     // (T, BATCH, N_VAR) fp16 scratch
        float* __restrict__ out,         // (T, N_VAR, BATCH) final
        int* __restrict__ flags) {       // T_ITERS counters
    __shared__ __align__(16) _Float16 msg[SLOT_MAX];   // 72 KB
    const int tid = threadIdx.x;
    const size_t SLICE = (size_t)N_VAR * BATCH;

    if (blockIdx.x < BATCH) {
        // ================= BP producer role =================
        const int b = blockIdx.x;
        for (int i = tid; i < SLOT_MAX; i += 1024) msg[i] = (_Float16)0.0f;

        const float g = 1.0f /
            (1.0f + __builtin_amdgcn_exp2f(-gamma_logit[0] * LOG2E));
        const float om = 1.0f - g;
        const float AT1 = atanh2(1.0f);

        float chn_r[8];
        float v2c_r[8][3];
        int4 s4r[8];
        int desc_r[4];
#pragma unroll
        for (int k = 0; k < 8; ++k) {
            int v = tid + k * 1024;
            chn_r[k] = chn[(size_t)v * BATCH + b];
            s4r[k] = slot4[v];
            v2c_r[k][0] = 0.0f; v2c_r[k][1] = 0.0f; v2c_r[k][2] = 0.0f;
        }
#pragma unroll
        for (int m = 0; m < 4; ++m) desc_r[m] = s_desc_g[m * 1024 + tid];
        __syncthreads();

        for (int t = 0; t < T_ITERS; ++t) {
            // ---- phase A: variables (8/thread), in-place c2v -> x ----
#pragma unroll
            for (int k = 0; k < 8; ++k) {
                int v = tid + k * 1024;
                int4 s4 = s4r[k];
                float c0 = (float)msg[s4.x];
                float c1 = (float)msg[s4.y];
                float c2 = (float)msg[s4.z];
                float post = chn_r[k] + c0 + c1 + c2;
                if (t > 0) {
                    __builtin_nontemporal_store((_Float16)post,
                        &outT[(size_t)(t - 1) * SLICE + (size_t)b * N_VAR + v]);
                }
                float vn0 = g * (post - c0) + om * v2c_r[k][0];
                float vn1 = g * (post - c1) + om * v2c_r[k][1];
                float vn2 = g * (post - c2) + om * v2c_r[k][2];
                v2c_r[k][0] = vn0; v2c_r[k][1] = vn1; v2c_r[k][2] = vn2;
                msg[s4.x] = (_Float16)fminf(fmaxf(vn0, -15.0f), 15.0f);
                msg[s4.y] = (_Float16)fminf(fmaxf(vn1, -15.0f), 15.0f);
                msg[s4.z] = (_Float16)fminf(fmaxf(vn2, -15.0f), 15.0f);
            }
            __syncthreads();
            if (t > 0 && tid == 0) {
                __threadfence();                       // L2 writeback
                __hip_atomic_fetch_add(&flags[t - 1], 1, __ATOMIC_RELEASE,
                                       __HIP_MEMORY_SCOPE_AGENT);
            }

            // ---- phase B: checks (4/thread, degree-sorted) ----
#pragma unroll
            for (int m = 0; m < 4; ++m) {
                int desc = desc_r[m];
                int base = desc >> 5;
                int deg = desc & 31;
                if (deg == 1) {
                    msg[base] = (_Float16)AT1;
                } else if (deg > 1) {
                    int nw = (deg + 3) >> 2;
                    h4 raw[6];
#pragma unroll
                    for (int w = 0; w < 6; ++w)
                        if (w < nw) raw[w] = *(const h4*)&msg[base + 4 * w];
                    float tv[ELLW];
                    float P = 1.0f;
#pragma unroll
                    for (int j = 0; j < ELLW; ++j)
                        if (j < deg) {
                            tv[j] = tanh_half((float)raw[j >> 2][j & 3]);
                            P *= tv[j];
                        }
#pragma unroll
                    for (int w = 0; w < 6; ++w)
                        if (w < nw) {
                            h4 out_w;
#pragma unroll
                            for (int q = 0; q < 4; ++q) {
                                int j = 4 * w + q;
                                float m2 = 0.0f;
                                if (j < deg)          // wave-uniform (sorted)
                                    m2 = atanh2(P * rcp_nr(tv[j]));
                                out_w[q] = (_Float16)m2;
                            }
                            *(h4*)&msg[base + 4 * w] = out_w;
                        }
                }
            }
            __syncthreads();
        }

        // ---- final posterior slice (after last check update) ----
#pragma unroll
        for (int k = 0; k < 8; ++k) {
            int v = tid + k * 1024;
            int4 s4 = s4r[k];
            float post = chn_r[k] + (float)msg[s4.x] + (float)msg[s4.y] +
                         (float)msg[s4.z];
            __builtin_nontemporal_store((_Float16)post,
                &outT[(size_t)(T_ITERS - 1) * SLICE + (size_t)b * N_VAR + v]);
        }
        __syncthreads();
        if (tid == 0) {
            __threadfence();
            __hip_atomic_fetch_add(&flags[T_ITERS - 1], 1, __ATOMIC_RELEASE,
                                   __HIP_MEMORY_SCOPE_AGENT);
        }
    } else {
        // ================= transpose worker role =================
        const int w = blockIdx.x - BATCH;          // 0..127
        const int lx = tid & 31;
        const int ly = tid >> 5;                   // 0..31
        float (*tile)[33] = (float(*)[33])msg;     // 4.2 KB of the LDS block

        for (int t = 0; t < T_ITERS; ++t) {
            if (tid == 0) {
                while (__hip_atomic_load(&flags[t], __ATOMIC_ACQUIRE,
                                         __HIP_MEMORY_SCOPE_AGENT) < BATCH)
                    __builtin_amdgcn_s_sleep(8);
            }
            __syncthreads();
            __threadfence();                       // acquire: invalidate caches

            const _Float16* s = outT + (size_t)t * SLICE;
            float* d = out + (size_t)t * SLICE;
#pragma unroll
            for (int i = 0; i < 8; ++i) {
                int tile_id = w + i * NWK;         // 0..1023
                int v0 = (tile_id >> 2) * 32;
                int b0 = (tile_id & 3) * 32;
                tile[ly][lx] = (float)s[(size_t)(b0 + ly) * N_VAR + v0 + lx];
                __syncthreads();
                __builtin_nontemporal_store(tile[lx][ly],
                    &d[(size_t)(v0 + ly) * BATCH + b0 + lx]);
                __syncthreads();
            }
        }
    }
}

// ---------------- Launch ---------------------------------------------------

extern "C" void kernel_launch(void* const* d_in, const int* in_sizes, int n_in,
                              void* d_out, int out_size, void* d_ws, size_t ws_size,
                              hipStream_t stream) {
    const float* chn         = (const float*)d_in[0];
    const float* gamma_logit = (const float*)d_in[1];
    // d_in[2] = edge_var (deterministic: e/3) — not needed
    const int* edge_chk      = (const int*)d_in[3];
    float* out = (float*)d_out;

    // workspace layout
    int4* slot4   = (int4*)d_ws;                          // N_VAR
    int* slot_e   = (int*)(slot4 + N_VAR);                // N_EDGE
    int* ell_e    = slot_e + N_EDGE;                      // N_CHK*ELLW
    int* s_desc_g = ell_e + (size_t)N_CHK * ELLW;         // N_CHK
    int* flags    = s_desc_g + N_CHK;                     // T_ITERS (+pad)
    size_t table_bytes = (char*)(flags + 64) - (char*)d_ws;
    size_t outT_off = (table_bytes + 255) & ~(size_t)255;
    _Float16* outT = (_Float16*)((char*)d_ws + outT_off); // T*SLICE fp16

    (void)hipMemsetAsync(flags, 0, 64 * sizeof(int), stream);

    k_setup<<<1, 1024, 0, stream>>>(edge_chk, ell_e, slot_e, s_desc_g, slot4);

    k_fused<<<BATCH + NWK, 1024, 0, stream>>>(chn, gamma_logit, slot4,
                                              s_desc_g, outT, out, flags);
}

// Round 11
// 603.984 us; speedup vs baseline: 3.3587x; 3.3587x over previous
//
#include <hip/hip_runtime.h>
#include <math.h>

#define N_VAR 8192
#define N_CHK 4096
#define DV 3
#define N_EDGE (N_VAR * DV)
#define BATCH 128
#define T_ITERS 30
#define ELLW 24
#define SLOT_MAX (N_EDGE + 3 * N_CHK)   /* 36864: sum of padded degs bound */

#define LOG2E 1.44269504088896340736f
#define LN2   0.69314718055994530942f

typedef _Float16 h4 __attribute__((ext_vector_type(4)));

// tanh(x/2), sign preserved, |t| floored at 1e-7 (matches reference clamp);
// x pre-clipped to [-15,15]
__device__ __forceinline__ float tanh_half(float x) {
    float ex = __builtin_amdgcn_exp2f(x * LOG2E);              // e^x
    float t = 1.0f - 2.0f * __builtin_amdgcn_rcpf(ex + 1.0f);
    float s = (x < 0.0f) ? -1.0f : 1.0f;
    return s * fmaxf(fabsf(t), 1e-7f);
}

// 2*atanh(clip(p)) — reference's clip(-1+eps, 1-eps) then 2 atanh
__device__ __forceinline__ float atanh2(float p) {
    const float lim = 1.0f - 1e-7f;
    p = fminf(fmaxf(p, -lim), lim);
    return (__builtin_amdgcn_logf(1.0f + p) -
            __builtin_amdgcn_logf(1.0f - p)) * LN2;
}

// Newton-refined reciprocal (validated R8/R9, absmax 0.125)
__device__ __forceinline__ float rcp_nr(float x) {
    float r = __builtin_amdgcn_rcpf(x);
    return r * (2.0f - x * r);
}

// ---------------- fused graph build (one block; validated R10) --------------

__global__ __launch_bounds__(1024) void k_setup(
        const int* __restrict__ edge_chk,
        int* __restrict__ ell_e,        // N_CHK*ELLW global scratch
        int* __restrict__ slot_e,       // N_EDGE global scratch
        int* __restrict__ s_desc_g,     // N_CHK sorted check descriptors
        int4* __restrict__ slot4) {     // N_VAR
    __shared__ int deg[N_CHK];          // 16 KB
    __shared__ int chk_base_s[N_CHK];   // 16 KB
    __shared__ int hist[32], cursor[32], bbase[32], soff[32];
    const int tid = threadIdx.x;

    for (int i = tid; i < N_CHK; i += 1024) deg[i] = 0;
    if (tid < 32) { hist[tid] = 0; cursor[tid] = 0; }
    __syncthreads();

    // stage 0: ELL scatter
    for (int e = tid; e < N_EDGE; e += 1024) {
        int c = edge_chk[e];
        int pos = atomicAdd(&deg[c], 1);
        if (pos < ELLW) ell_e[c * ELLW + pos] = e;
    }
    __syncthreads();

    // stage 1: degree histogram (clamped)
    for (int c = tid; c < N_CHK; c += 1024) {
        int d = deg[c]; if (d > ELLW) { d = ELLW; deg[c] = d; }
        atomicAdd(&hist[d], 1);
    }
    __syncthreads();

    // stage 2: bucket bases (serial, 25 buckets)
    if (tid == 0) {
        int cb = 0, sb = 0;
        for (int d = 0; d <= ELLW; ++d) {
            bbase[d] = cb; soff[d] = sb;
            int pd = (d + 3) & ~3;
            cb += hist[d];
            sb += (d == 0) ? 0 : hist[d] * pd;
        }
    }
    __syncthreads();

    // stage 3: place checks into degree-sorted order, padded slot bases
    for (int c = tid; c < N_CHK; c += 1024) {
        int d = deg[c];
        int pd = (d + 3) & ~3;
        int pos = atomicAdd(&cursor[d], 1);
        int i = bbase[d] + pos;
        int base = soff[d] + pos * pd;
        s_desc_g[i] = (base << 5) | d;
        chk_base_s[c] = base;
    }
    __syncthreads();

    // stage 4: slot of each edge
    for (int gid = tid; gid < N_CHK * ELLW; gid += 1024) {
        int c = gid / ELLW;
        int j = gid - c * ELLW;
        if (j < deg[c]) slot_e[ell_e[gid]] = chk_base_s[c] + j;
    }
    __syncthreads();

    // stage 5: per-variable slot triplets
    for (int v = tid; v < N_VAR; v += 1024) {
        int4 s;
        s.x = slot_e[3 * v + 0];
        s.y = slot_e[3 * v + 1];
        s.z = slot_e[3 * v + 2];
        s.w = 0;
        slot4[v] = s;
    }
}

// ---------------- persistent per-batch-element BP (R9-validated) ------------
// One block per batch element. In-place LDS msg (72 KB): phase A reads c2v,
// writes x to the same slot (owner-exclusive); phase B b64 vector ops on
// 8B-aligned padded check rows, degree-sorted -> wave-uniform deg.
// v2c in f32 registers. Posterior slices stored fp16 to outT (t,b,v).

__global__ __launch_bounds__(1024) void k_bp2(
        const float* __restrict__ chn,
        const float* __restrict__ gamma_logit,
        const int4* __restrict__ slot4,
        const int* __restrict__ s_desc_g,
        _Float16* __restrict__ outT) {      // (T, BATCH, N_VAR) fp16
    __shared__ __align__(16) _Float16 msg[SLOT_MAX];
    const int b = blockIdx.x;
    const int tid = threadIdx.x;

    for (int i = tid; i < SLOT_MAX; i += 1024) msg[i] = (_Float16)0.0f;

    const float g = 1.0f / (1.0f + __builtin_amdgcn_exp2f(-gamma_logit[0] * LOG2E));
    const float om = 1.0f - g;
    const float AT1 = atanh2(1.0f);         // deg-1 extrinsic constant

    float chn_r[8];
    float v2c_r[8][3];
    int4 s4r[8];
    int desc_r[4];
#pragma unroll
    for (int k = 0; k < 8; ++k) {
        int v = tid + k * 1024;
        chn_r[k] = chn[(size_t)v * BATCH + b];
        s4r[k] = slot4[v];
        v2c_r[k][0] = 0.0f; v2c_r[k][1] = 0.0f; v2c_r[k][2] = 0.0f;
    }
#pragma unroll
    for (int m = 0; m < 4; ++m) desc_r[m] = s_desc_g[m * 1024 + tid];
    __syncthreads();

    const size_t SLICE = (size_t)N_VAR * BATCH;

    for (int t = 0; t < T_ITERS; ++t) {
        // ---- phase A: variables (8 per thread), in-place c2v -> x ----
#pragma unroll
        for (int k = 0; k < 8; ++k) {
            int v = tid + k * 1024;
            int4 s4 = s4r[k];
            float c0 = (float)msg[s4.x];
            float c1 = (float)msg[s4.y];
            float c2 = (float)msg[s4.z];
            float post = chn_r[k] + c0 + c1 + c2;
            if (t > 0) {
                __builtin_nontemporal_store((_Float16)post,
                    &outT[(size_t)(t - 1) * SLICE + (size_t)b * N_VAR + v]);
            }
            float vn0 = g * (post - c0) + om * v2c_r[k][0];
            float vn1 = g * (post - c1) + om * v2c_r[k][1];
            float vn2 = g * (post - c2) + om * v2c_r[k][2];
            v2c_r[k][0] = vn0; v2c_r[k][1] = vn1; v2c_r[k][2] = vn2;
            msg[s4.x] = (_Float16)fminf(fmaxf(vn0, -15.0f), 15.0f);
            msg[s4.y] = (_Float16)fminf(fmaxf(vn1, -15.0f), 15.0f);
            msg[s4.z] = (_Float16)fminf(fmaxf(vn2, -15.0f), 15.0f);
        }
        __syncthreads();

        // ---- phase B: checks (4 per thread, degree-sorted) ----
#pragma unroll
        for (int m = 0; m < 4; ++m) {
            int desc = desc_r[m];
            int base = desc >> 5;
            int deg = desc & 31;
            if (deg == 1) {
                msg[base] = (_Float16)AT1;
            } else if (deg > 1) {
                int nw = (deg + 3) >> 2;
                h4 raw[6];
#pragma unroll
                for (int w = 0; w < 6; ++w)
                    if (w < nw) raw[w] = *(const h4*)&msg[base + 4 * w];
                float tv[ELLW];
                float P = 1.0f;
#pragma unroll
                for (int j = 0; j < ELLW; ++j)
                    if (j < deg) {
                        tv[j] = tanh_half((float)raw[j >> 2][j & 3]);
                        P *= tv[j];
                    }
#pragma unroll
                for (int w = 0; w < 6; ++w)
                    if (w < nw) {
                        h4 out_w;
#pragma unroll
                        for (int q = 0; q < 4; ++q) {
                            int j = 4 * w + q;
                            float m2 = (j < deg) ? atanh2(P * rcp_nr(tv[j])) : 0.0f;
                            out_w[q] = (_Float16)m2;
                        }
                        *(h4*)&msg[base + 4 * w] = out_w;
                    }
            }
        }
        __syncthreads();
    }

    // ---- final posterior row (after last check update) ----
#pragma unroll
    for (int k = 0; k < 8; ++k) {
        int v = tid + k * 1024;
        int4 s4 = s4r[k];
        float post = chn_r[k] + (float)msg[s4.x] + (float)msg[s4.y] +
                     (float)msg[s4.z];
        __builtin_nontemporal_store((_Float16)post,
            &outT[(size_t)(T_ITERS - 1) * SLICE + (size_t)b * N_VAR + v]);
    }
}

// ---------------- transpose (T,B,V) fp16 -> (T,V,B) f32 ---------------------
// tile[b_local][v_local]; write dst[v][b] coalesced (consecutive lx -> b).

__global__ __launch_bounds__(256) void k_transpose(
        const _Float16* __restrict__ src, float* __restrict__ dst) {
    __shared__ float tile[32][33];
    int t = blockIdx.z;
    int v0 = blockIdx.x * 32;
    int b0 = blockIdx.y * 32;
    int lx = threadIdx.x;            // 32 wide
    int ly = threadIdx.y;            // 8
    const _Float16* s = src + (size_t)t * N_VAR * BATCH;
    float* d = dst + (size_t)t * N_VAR * BATCH;
#pragma unroll
    for (int i = 0; i < 32; i += 8)
        tile[ly + i][lx] = (float)s[(size_t)(b0 + ly + i) * N_VAR + v0 + lx];
    __syncthreads();
#pragma unroll
    for (int i = 0; i < 32; i += 8)
        __builtin_nontemporal_store(tile[lx][ly + i],
            &d[(size_t)(v0 + ly + i) * BATCH + b0 + lx]);
}

// ---------------- Launch ---------------------------------------------------

extern "C" void kernel_launch(void* const* d_in, const int* in_sizes, int n_in,
                              void* d_out, int out_size, void* d_ws, size_t ws_size,
                              hipStream_t stream) {
    const float* chn         = (const float*)d_in[0];
    const float* gamma_logit = (const float*)d_in[1];
    // d_in[2] = edge_var (deterministic: e/3) — not needed
    const int* edge_chk      = (const int*)d_in[3];
    float* out = (float*)d_out;

    // workspace layout
    int4* slot4   = (int4*)d_ws;                          // N_VAR
    int* slot_e   = (int*)(slot4 + N_VAR);                // N_EDGE
    int* ell_e    = slot_e + N_EDGE;                      // N_CHK*ELLW
    int* s_desc_g = ell_e + (size_t)N_CHK * ELLW;         // N_CHK
    size_t table_bytes = (char*)(s_desc_g + N_CHK) - (char*)d_ws;
    size_t outT_off = (table_bytes + 255) & ~(size_t)255;
    _Float16* outT = (_Float16*)((char*)d_ws + outT_off); // T*SLICE fp16

    k_setup<<<1, 1024, 0, stream>>>(edge_chk, ell_e, slot_e, s_desc_g, slot4);

    k_bp2<<<BATCH, 1024, 0, stream>>>(chn, gamma_logit, slot4, s_desc_g, outT);

    dim3 tg(N_VAR / 32, BATCH / 32, T_ITERS);
    dim3 tb(32, 8, 1);
    k_transpose<<<tg, tb, 0, stream>>>(outT, out);
}

// Round 12
// 550.030 us; speedup vs baseline: 3.6882x; 1.0981x over previous
//
#include <hip/hip_runtime.h>
#include <math.h>

#define N_VAR 8192
#define N_CHK 4096
#define DV 3
#define N_EDGE (N_VAR * DV)
#define BATCH 128
#define T_ITERS 30
#define ELLW 24
#define SLOT_MAX (N_EDGE + 3 * N_CHK)   /* 36864: sum of padded degs bound */

#define LOG2E 1.44269504088896340736f
#define LN2   0.69314718055994530942f

typedef _Float16 h4 __attribute__((ext_vector_type(4)));
typedef _Float16 h2 __attribute__((ext_vector_type(2)));

// tanh(x/2), sign preserved, |t| floored at 1e-7 (matches reference clamp);
// x pre-clipped to [-15,15]
__device__ __forceinline__ float tanh_half(float x) {
    float ex = __builtin_amdgcn_exp2f(x * LOG2E);              // e^x
    float t = 1.0f - 2.0f * __builtin_amdgcn_rcpf(ex + 1.0f);
    float s = (x < 0.0f) ? -1.0f : 1.0f;
    return s * fmaxf(fabsf(t), 1e-7f);
}

// 2*atanh(clip(p)) — reference's clip(-1+eps, 1-eps) then 2 atanh
__device__ __forceinline__ float atanh2(float p) {
    const float lim = 1.0f - 1e-7f;
    p = fminf(fmaxf(p, -lim), lim);
    return (__builtin_amdgcn_logf(1.0f + p) -
            __builtin_amdgcn_logf(1.0f - p)) * LN2;
}

// Newton-refined reciprocal (validated R8/R9, absmax 0.125)
__device__ __forceinline__ float rcp_nr(float x) {
    float r = __builtin_amdgcn_rcpf(x);
    return r * (2.0f - x * r);
}

// ---------------- graph build (R9-validated parallel chain) -----------------

__global__ void k_ell_scatter(const int* __restrict__ edge_chk,
                              int* __restrict__ deg_arr, int* __restrict__ ell_e) {
    int e = blockIdx.x * blockDim.x + threadIdx.x;
    if (e < N_EDGE) {
        int c = edge_chk[e];
        int pos = atomicAdd(&deg_arr[c], 1);
        if (pos < ELLW) ell_e[c * ELLW + pos] = e;   // store EDGE id
    }
}

__global__ void k_hist(const int* __restrict__ deg_arr, int* __restrict__ hist) {
    int c = blockIdx.x * 256 + threadIdx.x;
    if (c < N_CHK) {
        int d = deg_arr[c]; if (d > ELLW) d = ELLW;
        atomicAdd(&hist[d], 1);
    }
}

// serial prefix over 25 degree buckets: check-index base + padded-slot base
__global__ void k_buckets(const int* __restrict__ hist,
                          int* __restrict__ bucket_base,
                          int* __restrict__ slot_off) {
    if (threadIdx.x == 0 && blockIdx.x == 0) {
        int cb = 0, sb = 0;
        for (int d = 0; d <= ELLW; ++d) {
            bucket_base[d] = cb;
            slot_off[d] = sb;
            int pd = (d == 0) ? 0 : ((d + 3) & ~3);
            cb += hist[d];
            sb += hist[d] * pd;
        }
    }
}

// place each check into its degree bucket: sorted desc + per-check base
__global__ void k_place(const int* __restrict__ deg_arr, int* __restrict__ cursor,
                        const int* __restrict__ bucket_base,
                        const int* __restrict__ slot_off,
                        int* __restrict__ s_desc_g, int* __restrict__ chk_base) {
    int c = blockIdx.x * 256 + threadIdx.x;
    if (c < N_CHK) {
        int d = deg_arr[c]; if (d > ELLW) d = ELLW;
        int pd = (d + 3) & ~3;
        int pos = atomicAdd(&cursor[d], 1);
        int i = bucket_base[d] + pos;
        int base = slot_off[d] + pos * pd;
        s_desc_g[i] = (base << 5) | d;
        chk_base[c] = base;
    }
}

// slot_e[e] = padded compact slot of edge e
__global__ void k_slotmap2(const int* __restrict__ ell_e,
                           const int* __restrict__ deg_arr,
                           const int* __restrict__ chk_base,
                           int* __restrict__ slot_e) {
    int gid = blockIdx.x * 256 + threadIdx.x;
    if (gid < N_CHK * ELLW) {
        int c = gid / ELLW;
        int j = gid - c * ELLW;
        int d = deg_arr[c]; if (d > ELLW) d = ELLW;
        if (j < d) slot_e[ell_e[gid]] = chk_base[c] + j;
    }
}

// slot4[v] = slots of v's 3 edges
__global__ void k_slot4(const int* __restrict__ slot_e, int4* __restrict__ slot4) {
    int v = blockIdx.x * 256 + threadIdx.x;
    if (v < N_VAR) {
        int4 s;
        s.x = slot_e[3 * v + 0];
        s.y = slot_e[3 * v + 1];
        s.z = slot_e[3 * v + 2];
        s.w = 0;
        slot4[v] = s;
    }
}

// ---------------- persistent per-batch-element BP (R9/R11-validated) --------
// One block per batch element. In-place LDS msg (72 KB): phase A reads c2v,
// writes x to the same slot (owner-exclusive); phase B b64 vector ops on
// 8B-aligned padded check rows, degree-sorted -> wave-uniform deg.
// v2c in f32 registers. Posterior slices stored fp16 to outT (t,b,v).

__global__ __launch_bounds__(1024) void k_bp2(
        const float* __restrict__ chn,
        const float* __restrict__ gamma_logit,
        const int4* __restrict__ slot4,
        const int* __restrict__ s_desc_g,
        _Float16* __restrict__ outT) {      // (T, BATCH, N_VAR) fp16
    __shared__ __align__(16) _Float16 msg[SLOT_MAX];
    const int b = blockIdx.x;
    const int tid = threadIdx.x;

    for (int i = tid; i < SLOT_MAX; i += 1024) msg[i] = (_Float16)0.0f;

    const float g = 1.0f / (1.0f + __builtin_amdgcn_exp2f(-gamma_logit[0] * LOG2E));
    const float om = 1.0f - g;
    const float AT1 = atanh2(1.0f);         // deg-1 extrinsic constant

    float chn_r[8];
    float v2c_r[8][3];
    int4 s4r[8];
    int desc_r[4];
#pragma unroll
    for (int k = 0; k < 8; ++k) {
        int v = tid + k * 1024;
        chn_r[k] = chn[(size_t)v * BATCH + b];
        s4r[k] = slot4[v];
        v2c_r[k][0] = 0.0f; v2c_r[k][1] = 0.0f; v2c_r[k][2] = 0.0f;
    }
#pragma unroll
    for (int m = 0; m < 4; ++m) desc_r[m] = s_desc_g[m * 1024 + tid];
    __syncthreads();

    const size_t SLICE = (size_t)N_VAR * BATCH;

    for (int t = 0; t < T_ITERS; ++t) {
        // ---- phase A: variables (8 per thread), in-place c2v -> x ----
#pragma unroll
        for (int k = 0; k < 8; ++k) {
            int v = tid + k * 1024;
            int4 s4 = s4r[k];
            float c0 = (float)msg[s4.x];
            float c1 = (float)msg[s4.y];
            float c2 = (float)msg[s4.z];
            float post = chn_r[k] + c0 + c1 + c2;
            if (t > 0) {
                __builtin_nontemporal_store((_Float16)post,
                    &outT[(size_t)(t - 1) * SLICE + (size_t)b * N_VAR + v]);
            }
            float vn0 = g * (post - c0) + om * v2c_r[k][0];
            float vn1 = g * (post - c1) + om * v2c_r[k][1];
            float vn2 = g * (post - c2) + om * v2c_r[k][2];
            v2c_r[k][0] = vn0; v2c_r[k][1] = vn1; v2c_r[k][2] = vn2;
            msg[s4.x] = (_Float16)fminf(fmaxf(vn0, -15.0f), 15.0f);
            msg[s4.y] = (_Float16)fminf(fmaxf(vn1, -15.0f), 15.0f);
            msg[s4.z] = (_Float16)fminf(fmaxf(vn2, -15.0f), 15.0f);
        }
        __syncthreads();

        // ---- phase B: checks (4 per thread, degree-sorted) ----
#pragma unroll
        for (int m = 0; m < 4; ++m) {
            int desc = desc_r[m];
            int base = desc >> 5;
            int deg = desc & 31;
            if (deg == 1) {
                msg[base] = (_Float16)AT1;
            } else if (deg > 1) {
                int nw = (deg + 3) >> 2;
                h4 raw[6];
#pragma unroll
                for (int w = 0; w < 6; ++w)
                    if (w < nw) raw[w] = *(const h4*)&msg[base + 4 * w];
                float tv[ELLW];
                float P = 1.0f;
#pragma unroll
                for (int j = 0; j < ELLW; ++j)
                    if (j < deg) {
                        tv[j] = tanh_half((float)raw[j >> 2][j & 3]);
                        P *= tv[j];
                    }
#pragma unroll
                for (int w = 0; w < 6; ++w)
                    if (w < nw) {
                        h4 out_w;
#pragma unroll
                        for (int q = 0; q < 4; ++q) {
                            int j = 4 * w + q;
                            float m2 = (j < deg) ? atanh2(P * rcp_nr(tv[j])) : 0.0f;
                            out_w[q] = (_Float16)m2;
                        }
                        *(h4*)&msg[base + 4 * w] = out_w;
                    }
            }
        }
        __syncthreads();
    }

    // ---- final posterior row (after last check update) ----
#pragma unroll
    for (int k = 0; k < 8; ++k) {
        int v = tid + k * 1024;
        int4 s4 = s4r[k];
        float post = chn_r[k] + (float)msg[s4.x] + (float)msg[s4.y] +
                     (float)msg[s4.z];
        __builtin_nontemporal_store((_Float16)post,
            &outT[(size_t)(T_ITERS - 1) * SLICE + (size_t)b * N_VAR + v]);
    }
}

// ---------------- transpose (T,B,V) fp16 -> (T,V,B) f32 ---------------------
// 64v x 32b tiles. Read: each lane loads an h2 pair (4B/lane, coalesced
// 128B/wave-row). Write: consecutive lx -> consecutive b (coalesced f32).
// tile[64][33]: read stores 2-way bank aliasing (free, m136); write reads
// bank-conflict-free ((j+ly)*33+lx mod 32 distinct across lx).

__global__ __launch_bounds__(256) void k_transpose(
        const _Float16* __restrict__ src, float* __restrict__ dst) {
    __shared__ float tile[64][33];
    int t = blockIdx.z;
    int v0 = blockIdx.x * 64;
    int b0 = blockIdx.y * 32;
    int lx = threadIdx.x;            // 32 wide
    int ly = threadIdx.y;            // 8
    const _Float16* s = src + (size_t)t * N_VAR * BATCH;
    float* d = dst + (size_t)t * N_VAR * BATCH;
#pragma unroll
    for (int i = 0; i < 32; i += 8) {
        int bl = ly + i;
        h2 pv = *(const h2*)&s[(size_t)(b0 + bl) * N_VAR + v0 + 2 * lx];
        tile[2 * lx + 0][bl] = (float)pv.x;
        tile[2 * lx + 1][bl] = (float)pv.y;
    }
    __syncthreads();
#pragma unroll
    for (int j = 0; j < 64; j += 8)
        __builtin_nontemporal_store(tile[j + ly][lx],
            &d[(size_t)(v0 + j + ly) * BATCH + b0 + lx]);
}

// ---------------- Launch ---------------------------------------------------

extern "C" void kernel_launch(void* const* d_in, const int* in_sizes, int n_in,
                              void* d_out, int out_size, void* d_ws, size_t ws_size,
                              hipStream_t stream) {
    const float* chn         = (const float*)d_in[0];
    const float* gamma_logit = (const float*)d_in[1];
    // d_in[2] = edge_var (deterministic: e/3) — not needed
    const int* edge_chk      = (const int*)d_in[3];
    float* out = (float*)d_out;

    // workspace layout
    int4* slot4      = (int4*)d_ws;                        // N_VAR
    int* slot_e      = (int*)(slot4 + N_VAR);              // N_EDGE
    int* ell_e       = slot_e + N_EDGE;                    // N_CHK*ELLW
    int* deg_arr     = ell_e + (size_t)N_CHK * ELLW;       // N_CHK
    int* chk_base    = deg_arr + N_CHK;                    // N_CHK
    int* s_desc_g    = chk_base + N_CHK;                   // N_CHK
    int* hist        = s_desc_g + N_CHK;                   // 32
    int* cursor      = hist + 32;                          // 32
    int* bucket_base = cursor + 32;                        // 32
    int* slot_off    = bucket_base + 32;                   // 32
    size_t table_bytes = (char*)(slot_off + 32) - (char*)d_ws;
    size_t outT_off = (table_bytes + 255) & ~(size_t)255;
    _Float16* outT = (_Float16*)((char*)d_ws + outT_off);  // T*SLICE fp16

    (void)hipMemsetAsync(deg_arr, 0, N_CHK * sizeof(int), stream);
    (void)hipMemsetAsync(hist, 0, 64 * sizeof(int), stream);   // hist + cursor

    k_ell_scatter<<<(N_EDGE + 255) / 256, 256, 0, stream>>>(edge_chk, deg_arr,
                                                            ell_e);
    k_hist<<<N_CHK / 256, 256, 0, stream>>>(deg_arr, hist);
    k_buckets<<<1, 64, 0, stream>>>(hist, bucket_base, slot_off);
    k_place<<<N_CHK / 256, 256, 0, stream>>>(deg_arr, cursor, bucket_base,
                                             slot_off, s_desc_g, chk_base);
    k_slotmap2<<<(N_CHK * ELLW + 255) / 256, 256, 0, stream>>>(ell_e, deg_arr,
                                                               chk_base, slot_e);
    k_slot4<<<N_VAR / 256, 256, 0, stream>>>(slot_e, slot4);

    k_bp2<<<BATCH, 1024, 0, stream>>>(chn, gamma_logit, slot4, s_desc_g, outT);

    dim3 tg(N_VAR / 64, BATCH / 32, T_ITERS);
    dim3 tb(32, 8, 1);
    k_transpose<<<tg, tb, 0, stream>>>(outT, out);
}